// Round 2
// baseline (1985.305 us; speedup 1.0000x reference)
//
#include <hip/hip_runtime.h>
#include <math.h>

#define B   64
#define T   512
#define I0  256
#define H   512
#define M   (B*T)

#define NGR    4         // batch groups (16 batches each -> MFMA M=16)
#define BGR    16
#define RSLOTS 64        // ring depth (power of 2) -> 4MB per ring
#define RESET_D 8        // producer resets slot r+8 (= step r-56 data)
#define SLOT_US (B*H)    // ushorts per ring slot
#define RING_US ((size_t)RSLOTS*SLOT_US)

#define NB1 64           // layer-1 blocks: 4 groups x 16 tile-pairs (32 cols)
#define NB2 64           // layer-2 blocks
#define POLL_BUDGET 4000000L

typedef __attribute__((ext_vector_type(8))) short short8;
typedef __attribute__((ext_vector_type(4))) float floatx4;

static __device__ __forceinline__ unsigned short f2bf(float f) {
  unsigned u = __float_as_uint(f);
  u += 0x7fff + ((u >> 16) & 1);          // RNE
  return (unsigned short)(u >> 16);
}

// fast tanh: 1 - 2/(e^{2x}+1). |err| ~1e-6, saturates correctly at +/-1.
static __device__ __forceinline__ float ftanh(float x) {
  float e = __expf(2.0f * x);
  return 1.0f - 2.0f * __builtin_amdgcn_rcpf(e + 1.0f);
}

// nonzero iff any halfword of v == 0xFFFF (the bf16 sentinel)
static __device__ __forceinline__ unsigned long long sentmask(unsigned long long v) {
  unsigned long long w = ~v;
  return (w - 0x0001000100010001ULL) & ~w & 0x8000800080008000ULL;
}

// ---------------------------------------------------------------------------
// fp32 GEMM for layer-1 input projection: xw[M,H] = x[M,I0] * Wih0[H,I0]^T
// ---------------------------------------------------------------------------
template<int K>
__global__ __launch_bounds__(256)
void gemm_awt(const float* __restrict__ A, const float* __restrict__ W,
              float* __restrict__ C) {
  __shared__ float As[16][68];
  __shared__ float Bs[16][68];
  const int tid = threadIdx.x;
  const int tx = tid & 15, ty = tid >> 4;
  const int m0 = blockIdx.x * 64, n0 = blockIdx.y * 64;
  float acc[4][4] = {};
  for (int k0 = 0; k0 < K; k0 += 16) {
    {
      int e = tid * 4;
      int m = e >> 4, k = e & 15;
      float4 v = *(const float4*)&A[(m0 + m) * K + k0 + k];
      As[k][m] = v.x; As[k+1][m] = v.y; As[k+2][m] = v.z; As[k+3][m] = v.w;
      float4 w = *(const float4*)&W[(n0 + m) * K + k0 + k];
      Bs[k][m] = w.x; Bs[k+1][m] = w.y; Bs[k+2][m] = w.z; Bs[k+3][m] = w.w;
    }
    __syncthreads();
    #pragma unroll
    for (int k = 0; k < 16; ++k) {
      float a[4], w[4];
      *(float4*)a = *(const float4*)&As[k][ty*4];
      *(float4*)w = *(const float4*)&Bs[k][tx*4];
      #pragma unroll
      for (int i = 0; i < 4; ++i)
        #pragma unroll
        for (int j = 0; j < 4; ++j)
          acc[i][j] += a[i] * w[j];
    }
    __syncthreads();
  }
  #pragma unroll
  for (int i = 0; i < 4; ++i) {
    float4 r;
    r.x = acc[i][0]; r.y = acc[i][1]; r.z = acc[i][2]; r.w = acc[i][3];
    *(float4*)&C[(m0 + ty*4 + i) * H + n0 + tx*4] = r;
  }
}

// ---------------------------------------------------------------------------
// Pack [H,H] fp32 weight into bf16 B-fragment lane order:
// dst layout [tile=32][kt=16][lane=64][8 us]
// ---------------------------------------------------------------------------
__global__ __launch_bounds__(256)
void pack_w(const float* __restrict__ W, unsigned short* __restrict__ dst) {
  int idx = blockIdx.x * 256 + threadIdx.x;   // over 16*2*16*64 = 32768
  int l = idx & 63, i = (idx >> 6) & 15, tau = (idx >> 10) & 1, c = idx >> 11;
  int col = c * 32 + tau * 16 + (l & 15);
  int k0  = i * 32 + (l >> 4) * 8;
  const float* src = &W[col * H + k0];
  unsigned v[4];
  #pragma unroll
  for (int j = 0; j < 4; ++j) {
    unsigned lo = f2bf(src[2*j]);
    unsigned hi = f2bf(src[2*j + 1]);
    v[j] = lo | (hi << 16);
  }
  *(uint4*)&dst[(size_t)idx * 8] = make_uint4(v[0], v[1], v[2], v[3]);
}

// ---------------------------------------------------------------------------
// Wave-autonomous pipelined recurrence. 128 blocks x 1 wave (64 threads):
//   blocks [0,64)  : layer 1, (group g, 32-col tile pair). Whh0 in VGPRs.
//   blocks [64,128): layer 2, (group g, 32-col tile pair). Whh1 in VGPRs,
//                    Wih1 in LDS (off the recurrence-critical path).
// No barriers, no LDS staging of h: each wave loads its MFMA A-fragments
// DIRECTLY from the ring with sentinel-polling (the winning poll loads are
// the operands). Rings are depth-64 [slot][B][H] bf16, sentinel 0xFFFF;
// producers reset slot r+RESET_D (data of step r-56), so consumers may lag
// up to 55 steps. A progress array + back-pressure (L1 stalls if layer 2
// lags > 32 steps, checked every 8) makes over-run impossible; layer 2
// never waits on future layer-1 data, so no deadlock. Watchdogs bail
// instead of hanging.
// ---------------------------------------------------------------------------
__global__ __launch_bounds__(64)
void rnn_fused(const float* __restrict__ xw,
               const unsigned short* __restrict__ wp0,  // Whh0 packed
               const unsigned short* __restrict__ wp1,  // Wih1 packed
               const unsigned short* __restrict__ wp2,  // Whh1 packed
               unsigned short* __restrict__ ring0,      // [RSLOTS][B][H] bf16
               unsigned short* __restrict__ ring1,      // [RSLOTS][B][H] bf16
               float* __restrict__ dout,                // [B][T][H]
               int* __restrict__ prog)                  // [NGR][16] L2 progress
{
  __shared__ unsigned short wi_lds[16384];   // L2: Wih1 2 tiles (32KB)
  const int lane = threadIdx.x;
  const int mrow = lane & 15, quad = lane >> 4;
  long cnt = 0;

  if (blockIdx.x < NB1) {
    // ============================ layer 1 ============================
    const int g  = blockIdx.x & 3;
    const int wp = blockIdx.x >> 2;          // 0..15
    const int t0 = wp * 2;                   // tile index (16 cols each)
    const int b0 = g * BGR;
    short8 w0[16], w1[16];
    #pragma unroll
    for (int kt = 0; kt < 16; ++kt) {
      w0[kt] = *(const short8*)(wp0 + (size_t)(((t0    ) * 16 + kt) * 64 + lane) * 8);
      w1[kt] = *(const short8*)(wp0 + (size_t)(((t0 + 1) * 16 + kt) * 64 + lane) * 8);
    }
    const int ccol0 = t0 * 16 + mrow, ccol1 = ccol0 + 16;
    int* pg = prog + g * 16;

    for (int r = 0; r < T; ++r) {
      // xw prefetch: in flight while we poll
      float xv0[4], xv1[4];
      #pragma unroll
      for (int i = 0; i < 4; ++i) {
        size_t base = ((size_t)(b0 + quad * 4 + i) * T + r) * H;
        xv0[i] = xw[base + ccol0];
        xv1[i] = xw[base + ccol1];
      }
      floatx4 acc0 = {0.f,0.f,0.f,0.f}, acc1 = {0.f,0.f,0.f,0.f};
      if (r >= 1) {
        const unsigned long long* rb = (const unsigned long long*)
            (ring0 + (size_t)((r - 1) & (RSLOTS - 1)) * SLOT_US
                   + (size_t)(b0 + mrow) * H);
        unsigned long long hv[32];
        for (;;) {
          #pragma unroll
          for (int kt = 0; kt < 16; ++kt) {
            hv[2*kt]   = __hip_atomic_load(rb + kt * 8 + quad * 2,
                                           __ATOMIC_RELAXED, __HIP_MEMORY_SCOPE_AGENT);
            hv[2*kt+1] = __hip_atomic_load(rb + kt * 8 + quad * 2 + 1,
                                           __ATOMIC_RELAXED, __HIP_MEMORY_SCOPE_AGENT);
          }
          unsigned long long bad = 0;
          #pragma unroll
          for (int j = 0; j < 32; ++j) bad |= sentmask(hv[j]);
          if (__all(bad == 0) || ++cnt > POLL_BUDGET) break;
        }
        #pragma unroll
        for (int kt = 0; kt < 16; ++kt) {
          union { unsigned long long u[2]; short8 s; } a;
          a.u[0] = hv[2*kt]; a.u[1] = hv[2*kt+1];
          acc0 = __builtin_amdgcn_mfma_f32_16x16x32_bf16(a.s, w0[kt], acc0, 0, 0, 0);
          acc1 = __builtin_amdgcn_mfma_f32_16x16x32_bf16(a.s, w1[kt], acc1, 0, 0, 0);
        }
      }
      unsigned short* wdst = ring0 + (size_t)(r & (RSLOTS - 1)) * SLOT_US;
      unsigned short* wrst = ring0 + (size_t)((r + RESET_D) & (RSLOTS - 1)) * SLOT_US;
      #pragma unroll
      for (int i = 0; i < 4; ++i) {
        size_t brow = (size_t)(b0 + quad * 4 + i) * H;
        __hip_atomic_store(wdst + brow + ccol0, f2bf(ftanh(acc0[i] + xv0[i])),
                           __ATOMIC_RELAXED, __HIP_MEMORY_SCOPE_AGENT);
        __hip_atomic_store(wdst + brow + ccol1, f2bf(ftanh(acc1[i] + xv1[i])),
                           __ATOMIC_RELAXED, __HIP_MEMORY_SCOPE_AGENT);
      }
      #pragma unroll
      for (int i = 0; i < 4; ++i) {     // sentinel resets (off critical path)
        size_t brow = (size_t)(b0 + quad * 4 + i) * H;
        __hip_atomic_store(wrst + brow + ccol0, (unsigned short)0xFFFFu,
                           __ATOMIC_RELAXED, __HIP_MEMORY_SCOPE_AGENT);
        __hip_atomic_store(wrst + brow + ccol1, (unsigned short)0xFFFFu,
                           __ATOMIC_RELAXED, __HIP_MEMORY_SCOPE_AGENT);
      }
      // back-pressure: never run >32 ahead of slowest layer-2 consumer
      if ((r & 7) == 0 && r >= 40) {
        for (;;) {
          int mn = 0x7fffffff;
          #pragma unroll
          for (int j = 0; j < 16; ++j) {
            int v = __hip_atomic_load(pg + j, __ATOMIC_RELAXED, __HIP_MEMORY_SCOPE_AGENT);
            mn = v < mn ? v : mn;
          }
          if (r - mn <= 32 || ++cnt > POLL_BUDGET) break;
          __builtin_amdgcn_s_sleep(8);
        }
      }
    }
  } else {
    // ============================ layer 2 ============================
    const int b2 = blockIdx.x - NB1;
    const int g  = b2 & 3;
    const int wp = b2 >> 2;
    const int t0 = wp * 2;
    const int b0 = g * BGR;
    {   // stage Wih1 tile pair into LDS (linear, conflict-free reads)
      const uint4* s = (const uint4*)(wp1 + (size_t)t0 * 8192);
      uint4* d = (uint4*)wi_lds;
      for (int i = lane; i < 2048; i += 64) d[i] = s[i];
    }
    short8 wh0[16], wh1[16];
    #pragma unroll
    for (int kt = 0; kt < 16; ++kt) {
      wh0[kt] = *(const short8*)(wp2 + (size_t)(((t0    ) * 16 + kt) * 64 + lane) * 8);
      wh1[kt] = *(const short8*)(wp2 + (size_t)(((t0 + 1) * 16 + kt) * 64 + lane) * 8);
    }
    __syncthreads();
    const int ccol0 = t0 * 16 + mrow, ccol1 = ccol0 + 16;
    int* pslot = prog + g * 16 + wp;

    for (int t = 0; t < T; ++t) {
      // ---- poll h1 = ring0[t] (we lag layer 1 -> usually ready first try)
      const unsigned long long* rb0 = (const unsigned long long*)
          (ring0 + (size_t)(t & (RSLOTS - 1)) * SLOT_US + (size_t)(b0 + mrow) * H);
      unsigned long long h1[32];
      for (;;) {
        #pragma unroll
        for (int kt = 0; kt < 16; ++kt) {
          h1[2*kt]   = __hip_atomic_load(rb0 + kt * 8 + quad * 2,
                                         __ATOMIC_RELAXED, __HIP_MEMORY_SCOPE_AGENT);
          h1[2*kt+1] = __hip_atomic_load(rb0 + kt * 8 + quad * 2 + 1,
                                         __ATOMIC_RELAXED, __HIP_MEMORY_SCOPE_AGENT);
        }
        unsigned long long bad = 0;
        #pragma unroll
        for (int j = 0; j < 32; ++j) bad |= sentmask(h1[j]);
        if (__all(bad == 0) || ++cnt > POLL_BUDGET) break;
      }
      // ---- issue own-recurrence loads; their IC latency hides under Wi1 work
      unsigned long long h2[32];
      const unsigned long long* rb1 = (const unsigned long long*)
          (ring1 + (size_t)((t - 1) & (RSLOTS - 1)) * SLOT_US + (size_t)(b0 + mrow) * H);
      if (t >= 1) {
        #pragma unroll
        for (int kt = 0; kt < 16; ++kt) {
          h2[2*kt]   = __hip_atomic_load(rb1 + kt * 8 + quad * 2,
                                         __ATOMIC_RELAXED, __HIP_MEMORY_SCOPE_AGENT);
          h2[2*kt+1] = __hip_atomic_load(rb1 + kt * 8 + quad * 2 + 1,
                                         __ATOMIC_RELAXED, __HIP_MEMORY_SCOPE_AGENT);
        }
      }
      // ---- Wih1 * h1 (weights from LDS)
      floatx4 acc0 = {0.f,0.f,0.f,0.f}, acc1 = {0.f,0.f,0.f,0.f};
      #pragma unroll
      for (int kt = 0; kt < 16; ++kt) {
        union { unsigned long long u[2]; short8 s; } a;
        a.u[0] = h1[2*kt]; a.u[1] = h1[2*kt+1];
        short8 bi0 = *(const short8*)(wi_lds + (size_t)((kt     ) * 64 + lane) * 8);
        short8 bi1 = *(const short8*)(wi_lds + (size_t)((16 + kt) * 64 + lane) * 8);
        acc0 = __builtin_amdgcn_mfma_f32_16x16x32_bf16(a.s, bi0, acc0, 0, 0, 0);
        acc1 = __builtin_amdgcn_mfma_f32_16x16x32_bf16(a.s, bi1, acc1, 0, 0, 0);
      }
      // ---- check h2 (first check uses preloaded values), then Whh1 * h2
      if (t >= 1) {
        for (;;) {
          unsigned long long bad = 0;
          #pragma unroll
          for (int j = 0; j < 32; ++j) bad |= sentmask(h2[j]);
          if (__all(bad == 0) || ++cnt > POLL_BUDGET) break;
          #pragma unroll
          for (int kt = 0; kt < 16; ++kt) {
            h2[2*kt]   = __hip_atomic_load(rb1 + kt * 8 + quad * 2,
                                           __ATOMIC_RELAXED, __HIP_MEMORY_SCOPE_AGENT);
            h2[2*kt+1] = __hip_atomic_load(rb1 + kt * 8 + quad * 2 + 1,
                                           __ATOMIC_RELAXED, __HIP_MEMORY_SCOPE_AGENT);
          }
        }
        #pragma unroll
        for (int kt = 0; kt < 16; ++kt) {
          union { unsigned long long u[2]; short8 s; } a;
          a.u[0] = h2[2*kt]; a.u[1] = h2[2*kt+1];
          acc0 = __builtin_amdgcn_mfma_f32_16x16x32_bf16(a.s, wh0[kt], acc0, 0, 0, 0);
          acc1 = __builtin_amdgcn_mfma_f32_16x16x32_bf16(a.s, wh1[kt], acc1, 0, 0, 0);
        }
      }
      // ---- epilogue: dout + ring1 publish + sentinel resets + progress
      unsigned short* wdst = ring1 + (size_t)(t & (RSLOTS - 1)) * SLOT_US;
      unsigned short* wrst = ring1 + (size_t)((t + RESET_D) & (RSLOTS - 1)) * SLOT_US;
      #pragma unroll
      for (int i = 0; i < 4; ++i) {
        int b = b0 + quad * 4 + i;
        float v0 = ftanh(acc0[i]);
        float v1 = ftanh(acc1[i]);
        __hip_atomic_store(wdst + (size_t)b * H + ccol0, f2bf(v0),
                           __ATOMIC_RELAXED, __HIP_MEMORY_SCOPE_AGENT);
        __hip_atomic_store(wdst + (size_t)b * H + ccol1, f2bf(v1),
                           __ATOMIC_RELAXED, __HIP_MEMORY_SCOPE_AGENT);
        dout[((size_t)b * T + t) * H + ccol0] = v0;
        dout[((size_t)b * T + t) * H + ccol1] = v1;
      }
      #pragma unroll
      for (int i = 0; i < 4; ++i) {
        int b = b0 + quad * 4 + i;
        __hip_atomic_store(wrst + (size_t)b * H + ccol0, (unsigned short)0xFFFFu,
                           __ATOMIC_RELAXED, __HIP_MEMORY_SCOPE_AGENT);
        __hip_atomic_store(wrst + (size_t)b * H + ccol1, (unsigned short)0xFFFFu,
                           __ATOMIC_RELAXED, __HIP_MEMORY_SCOPE_AGENT);
      }
      if ((t & 7) == 0 && lane == 0)
        __hip_atomic_store(pslot, t, __ATOMIC_RELAXED, __HIP_MEMORY_SCOPE_AGENT);
    }
  }
}

extern "C" void kernel_launch(void* const* d_in, const int* in_sizes, int n_in,
                              void* d_out, int out_size, void* d_ws, size_t ws_size,
                              hipStream_t stream) {
  const float* x    = (const float*)d_in[0];
  const float* Wih0 = (const float*)d_in[1];
  const float* Whh0 = (const float*)d_in[2];
  const float* Wih1 = (const float*)d_in[3];
  const float* Whh1 = (const float*)d_in[4];
  float* out = (float*)d_out;

  char* ws = (char*)d_ws;
  float* xw = (float*)ws;
  unsigned short* wp0 = (unsigned short*)(ws + (size_t)64*1024*1024);
  unsigned short* wp1 = (unsigned short*)(ws + (size_t)64*1024*1024 + 512*1024);
  unsigned short* wp2 = (unsigned short*)(ws + (size_t)64*1024*1024 + 1024*1024);
  unsigned short* ring0 = (unsigned short*)(ws + (size_t)64*1024*1024 + 1536*1024);
  unsigned short* ring1 = ring0 + RING_US;
  int* prog = (int*)(ring1 + RING_US);

  // sentinel-fill both rings (0xFFFF bf16 = -NaN; tanh never produces it)
  hipMemsetAsync(ring0, 0xFF, 2 * RING_US * sizeof(unsigned short), stream);
  hipMemsetAsync(prog, 0, NGR * 16 * sizeof(int), stream);

  pack_w<<<128, 256, 0, stream>>>(Whh0, wp0);
  pack_w<<<128, 256, 0, stream>>>(Wih1, wp1);
  pack_w<<<128, 256, 0, stream>>>(Whh1, wp2);

  dim3 gg(M/64, H/64);
  gemm_awt<I0><<<gg, 256, 0, stream>>>(x, Wih0, xw);

  rnn_fused<<<NB1 + NB2, 64, 0, stream>>>(
      xw, wp0, wp1, wp2, ring0, ring1, out, prog);
}